// Round 4
// baseline (224.490 us; speedup 1.0000x reference)
//
#include <hip/hip_runtime.h>
#include <hip/hip_fp16.h>

// Trilinear 3D-LUT apply: lut [1,3,33,33,33] f32, x [8,3,1024,1024] f32 in [0,1]
// out [8,3,1024,1024] f32.
//
// R3 post-mortem: all pipes <= 31us busy at dur=103us -> LATENCY-bound.
// LDS (143.8 KB) caps us at 1 block/CU (16 waves, 41% occ); unroll-1 loop
// exposes only 3 global loads per iteration. Fix = ILP: unroll x2, batch all
// loads -> all index math -> all 32 LDS gathers -> all FMAs -> stores.
// VGPR must stay <=128 for 4 waves/SIMD: __launch_bounds__(1024, 4).
// Kept from R1-R3: half2 b-pair packing (4 LDS reads/pixel), unconditional
// +D/+D2 offsets, XCD swizzle (FETCH 152->56 MB), nontemporal stores.

#define D   33
#define D2  (33 * 33)
#define D3  (33 * 33 * 33)      // 35937 half2 = 143,748 B LDS
#define HW  (1024 * 1024)
#define BATCH 8
#define QHW (HW / 4)            // float4 groups per plane (2^18)
#define NG  (BATCH * QHW)       // float4 groups per channel
#define CHUNKS 256
#define GPC (NG / CHUNKS)       // groups per chunk = 8192 (chunk never crosses batch: 2^18/8192=32)
#define THREADS 1024

typedef float v4f __attribute__((ext_vector_type(4)));

__global__ __launch_bounds__(THREADS, 4) void lut3d_kernel(
    const float* __restrict__ lut, const float* __restrict__ x,
    float* __restrict__ out)
{
    // XCD-aware swizzle: the 3 channel-blocks of a chunk share an XCD ->
    // x fetched from HBM once per chunk.
    const int id    = blockIdx.x;       // 0..767
    const int xcd   = id & 7;
    const int slot  = id >> 3;          // 0..95
    const int c     = slot % 3;         // output channel
    const int chunk = (slot / 3) * 8 + xcd;   // 0..255, bijective

    __shared__ __half2 ls[D3];
    {
        const float* lc = lut + c * D3;
        for (int i = threadIdx.x; i < D3; i += THREADS) {
            const int q  = i / D;
            const int b  = i - q * D;       // i % 33
            const float v0 = lc[i];
            const float v1 = (b < D - 1) ? lc[i + 1] : v0;
            ls[i] = __floats2half2_rn(v0, v1);
        }
    }
    __syncthreads();

    const int tid  = threadIdx.x;
    const int base = chunk * GPC;
    const int b    = base >> 18;                       // batch: constant per block
    const float* __restrict__ xb = x + (size_t)b * 3 * HW;
    float* __restrict__ ob = out + (size_t)b * 3 * HW + (size_t)c * HW;

    int off = (base & (QHW - 1)) * 4 + tid * 4;        // element offset in plane

    #pragma unroll 1
    for (int it = 0; it < GPC / THREADS; it += 2, off += 2 * THREADS * 4) {
        const int o0 = off, o1 = off + THREADS * 4;

        // --- phase 1: all global loads in flight (6 x dwordx4) ---
        const v4f xr0 = *(const v4f*)(xb + o0);
        const v4f xg0 = *(const v4f*)(xb + HW + o0);
        const v4f xB0 = *(const v4f*)(xb + 2 * HW + o0);
        const v4f xr1 = *(const v4f*)(xb + o1);
        const v4f xg1 = *(const v4f*)(xb + HW + o1);
        const v4f xB1 = *(const v4f*)(xb + 2 * HW + o1);

        // --- phase 2: index + fraction math for 8 pixels ---
        int   idxs[8];
        float frs[8], fgs[8], fbs[8];
        #pragma unroll
        for (int k = 0; k < 8; ++k) {
            const float rx = (k < 4) ? xr0[k & 3] : xr1[k & 3];
            const float gx = (k < 4) ? xg0[k & 3] : xg1[k & 3];
            const float bx = (k < 4) ? xB0[k & 3] : xB1[k & 3];
            const float vr = fminf(fmaxf(rx, 0.f), 1.f) * 32.f;
            const float vg = fminf(fmaxf(gx, 0.f), 1.f) * 32.f;
            const float vb = fminf(fmaxf(bx, 0.f), 1.f) * 32.f;
            const int r0 = min((int)vr, D - 2);
            const int g0 = min((int)vg, D - 2);
            const int b0 = min((int)vb, D - 2);
            frs[k] = vr - (float)r0;
            fgs[k] = vg - (float)g0;
            fbs[k] = vb - (float)b0;
            idxs[k] = r0 * D2 + g0 * D + b0;
        }

        // --- phase 3: all 32 LDS gathers in flight ---
        __half2 h[8][4];
        #pragma unroll
        for (int k = 0; k < 8; ++k) {
            const int idx = idxs[k];
            h[k][0] = ls[idx];
            h[k][1] = ls[idx + D];
            h[k][2] = ls[idx + D2];
            h[k][3] = ls[idx + D2 + D];
        }

        // --- phase 4: trilinear math ---
        v4f oo0, oo1;
        #pragma unroll
        for (int k = 0; k < 8; ++k) {
            const float fb = fbs[k], fg = fgs[k], fr = frs[k];
            const float c00 = fmaf(fb, __high2float(h[k][0]) - __low2float(h[k][0]), __low2float(h[k][0]));
            const float c01 = fmaf(fb, __high2float(h[k][1]) - __low2float(h[k][1]), __low2float(h[k][1]));
            const float c10 = fmaf(fb, __high2float(h[k][2]) - __low2float(h[k][2]), __low2float(h[k][2]));
            const float c11 = fmaf(fb, __high2float(h[k][3]) - __low2float(h[k][3]), __low2float(h[k][3]));
            const float c0  = fmaf(fg, c01 - c00, c00);
            const float c1  = fmaf(fg, c11 - c10, c10);
            const float r   = fmaf(fr, c1 - c0, c0);
            if (k < 4) oo0[k & 3] = r; else oo1[k & 3] = r;
        }

        __builtin_nontemporal_store(oo0, (v4f*)(ob + o0));
        __builtin_nontemporal_store(oo1, (v4f*)(ob + o1));
    }
}

extern "C" void kernel_launch(void* const* d_in, const int* in_sizes, int n_in,
                              void* d_out, int out_size, void* d_ws, size_t ws_size,
                              hipStream_t stream) {
    const float* lut = (const float*)d_in[0];   // [1,3,33,33,33]
    const float* x   = (const float*)d_in[1];   // [8,3,1024,1024]
    float* out = (float*)d_out;                 // [8,3,1024,1024]

    lut3d_kernel<<<dim3(3 * CHUNKS), THREADS, 0, stream>>>(lut, x, out);
}

// Round 5
// 223.724 us; speedup vs baseline: 1.0034x; 1.0034x over previous
//
#include <hip/hip_runtime.h>
#include <hip/hip_fp16.h>

// Trilinear 3D-LUT apply: lut [1,3,33,33,33] f32, x [8,3,1024,1024] f32 in [0,1]
// out [8,3,1024,1024] f32.
//
// R4 post-mortem: VGPR stuck at 52 -> compiler re-interleaved my batched
// phases; kernel stayed latency-bound (VALU 29%, LDS 27%, serial convoy).
// R5: true 3-stage software pipeline per wave, fenced with sched_barrier(0):
//   body(it): [load x(it+2)] [prep it+1] [gather it+1] FENCE [fma+store it]
// Every wait (vmcnt for prep, lgkmcnt for fma) is on ops issued one full body
// earlier -> pipes overlap; floor = max(VALU ~24k, LDS ~22k) cyc/block.
// LUT stored as (lo, hi-lo) half2 -> b-lerp is a single fma per corner.
// Kept: per-channel LDS cube (143.7 KB), XCD swizzle, NT stores.

#define D   33
#define D2  (33 * 33)
#define D3  (33 * 33 * 33)      // 35937 half2 = 143,748 B LDS
#define HW  (1024 * 1024)
#define QHW (HW / 4)            // float4 groups per plane (2^18)
#define CHUNKS 256
#define GPC 8192                // float4 groups per chunk (never crosses batch)
#define THREADS 1024
#define NIT (GPC / THREADS)     // 8 iterations per thread
#define STRIDE (THREADS * 4)    // element step per iteration

typedef float v4f __attribute__((ext_vector_type(4)));

__global__ __launch_bounds__(THREADS, 4) void lut3d_kernel(
    const float* __restrict__ lut, const float* __restrict__ x,
    float* __restrict__ out)
{
    // XCD-aware swizzle: 3 channel-blocks of a chunk share an XCD L2.
    const int id    = blockIdx.x;       // 0..767
    const int xcd   = id & 7;
    const int slot  = id >> 3;
    const int c     = slot % 3;
    const int chunk = (slot / 3) * 8 + xcd;

    __shared__ __half2 ls[D3];
    {
        const float* lc = lut + c * D3;
        for (int i = threadIdx.x; i < D3; i += THREADS) {
            const int q  = i / D;
            const int bb = i - q * D;              // i % 33
            const float v0 = lc[i];
            const float v1 = (bb < D - 1) ? lc[i + 1] : v0;
            ls[i] = __floats2half2_rn(v0, v1 - v0);   // (lo, delta)
        }
    }
    __syncthreads();

    const int base = chunk * GPC;
    const int b    = base >> 18;                   // batch: constant per block
    const float* __restrict__ xp = x + (size_t)b * 3 * HW;
    float* __restrict__ op = out + (size_t)b * 3 * HW + (size_t)c * HW;
    const int o0 = (base & (QHW - 1)) * 4 + threadIdx.x * 4;

#define LOADX(o, R, G, B) do { \
    (R) = *(const v4f*)(xp + (o)); \
    (G) = *(const v4f*)(xp + HW + (o)); \
    (B) = *(const v4f*)(xp + 2 * HW + (o)); } while (0)

#define PREP(XR, XG, XB, IDX, FR, FG, FB) do { \
    _Pragma("unroll") \
    for (int k = 0; k < 4; ++k) { \
        const float vr = fminf(fmaxf((XR)[k], 0.f), 1.f) * 32.f; \
        const float vg = fminf(fmaxf((XG)[k], 0.f), 1.f) * 32.f; \
        const float vb = fminf(fmaxf((XB)[k], 0.f), 1.f) * 32.f; \
        const int r0 = min((int)vr, D - 2); \
        const int g0 = min((int)vg, D - 2); \
        const int b0 = min((int)vb, D - 2); \
        (FR)[k] = vr - (float)r0; \
        (FG)[k] = vg - (float)g0; \
        (FB)[k] = vb - (float)b0; \
        (IDX)[k] = r0 * D2 + g0 * D + b0; } } while (0)

#define GATHER(IDX, H) do { \
    _Pragma("unroll") \
    for (int k = 0; k < 4; ++k) { \
        const int idx = (IDX)[k]; \
        (H)[k][0] = ls[idx]; \
        (H)[k][1] = ls[idx + D]; \
        (H)[k][2] = ls[idx + D2]; \
        (H)[k][3] = ls[idx + D2 + D]; } } while (0)

#define FMASTORE(o, FR, FG, FB, H) do { \
    v4f oo; \
    _Pragma("unroll") \
    for (int k = 0; k < 4; ++k) { \
        const float fb = (FB)[k], fg = (FG)[k], fr = (FR)[k]; \
        const float c00 = fmaf(fb, __high2float((H)[k][0]), __low2float((H)[k][0])); \
        const float c01 = fmaf(fb, __high2float((H)[k][1]), __low2float((H)[k][1])); \
        const float c10 = fmaf(fb, __high2float((H)[k][2]), __low2float((H)[k][2])); \
        const float c11 = fmaf(fb, __high2float((H)[k][3]), __low2float((H)[k][3])); \
        const float c0 = fmaf(fg, c01 - c00, c00); \
        const float c1 = fmaf(fg, c11 - c10, c10); \
        oo[k] = fmaf(fr, c1 - c0, c0); } \
    __builtin_nontemporal_store(oo, (v4f*)(op + (o))); } while (0)

    // ---- pipeline prologue: x for it=0,1; prep+gather for it=0 ----
    v4f xr1, xg1, xb1;
    int   idxA[4]; float frA[4], fgA[4], fbA[4]; __half2 hA[4][4];
    {
        v4f xr0, xg0, xb0;
        LOADX(o0, xr0, xg0, xb0);
        LOADX(o0 + STRIDE, xr1, xg1, xb1);
        PREP(xr0, xg0, xb0, idxA, frA, fgA, fbA);
        GATHER(idxA, hA);
    }

    // ---- steady state (fully unrolled; tail guards are compile-time) ----
    #pragma unroll
    for (int it = 0; it < NIT; ++it) {
        v4f nxr, nxg, nxb;
        if (it + 2 < NIT) LOADX(o0 + (it + 2) * STRIDE, nxr, nxg, nxb);
        int idxN[4]; float frN[4], fgN[4], fbN[4]; __half2 hN[4][4];
        if (it + 1 < NIT) {
            PREP(xr1, xg1, xb1, idxN, frN, fgN, fbN);
            GATHER(idxN, hN);
        }
        // Fence: gathers/loads for it+1/it+2 must be issued BEFORE the fma
        // phase below; this is the boundary the compiler kept collapsing.
        __builtin_amdgcn_sched_barrier(0);
        FMASTORE(o0 + it * STRIDE, frA, fgA, fbA, hA);
        // rotate (register renames after unroll)
        xr1 = nxr; xg1 = nxg; xb1 = nxb;
        #pragma unroll
        for (int k = 0; k < 4; ++k) {
            idxA[k] = idxN[k]; frA[k] = frN[k]; fgA[k] = fgN[k]; fbA[k] = fbN[k];
            hA[k][0] = hN[k][0]; hA[k][1] = hN[k][1];
            hA[k][2] = hN[k][2]; hA[k][3] = hN[k][3];
        }
    }

#undef LOADX
#undef PREP
#undef GATHER
#undef FMASTORE
}

extern "C" void kernel_launch(void* const* d_in, const int* in_sizes, int n_in,
                              void* d_out, int out_size, void* d_ws, size_t ws_size,
                              hipStream_t stream) {
    const float* lut = (const float*)d_in[0];   // [1,3,33,33,33]
    const float* x   = (const float*)d_in[1];   // [8,3,1024,1024]
    float* out = (float*)d_out;                 // [8,3,1024,1024]

    lut3d_kernel<<<dim3(3 * CHUNKS), THREADS, 0, stream>>>(lut, x, out);
}